// Round 15
// baseline (249.509 us; speedup 1.0000x reference)
//
#include <hip/hip_runtime.h>
#include <hip/hip_bf16.h>

// ---------- types ----------
typedef __bf16 bf16x8 __attribute__((ext_vector_type(8)));
typedef float  f32x4  __attribute__((ext_vector_type(4)));

__device__ __forceinline__ f32x4 mfma16(bf16x8 a, bf16x8 b, f32x4 c) {
    return __builtin_amdgcn_mfma_f32_16x16x32_bf16(a, b, c, 0, 0, 0);
}

__device__ __forceinline__ void gload_lds16(const void* g, void* l) {
    __builtin_amdgcn_global_load_lds(
        (const __attribute__((address_space(1))) void*)g,
        (__attribute__((address_space(3))) void*)l, 16, 0, 0);
}

__device__ __forceinline__ float bf2f(unsigned short u) {
    unsigned int x = (unsigned int)u << 16;
    return __builtin_bit_cast(float, x);
}
__device__ __forceinline__ unsigned short f2bf(float f) {
    return __builtin_bit_cast(unsigned short, __float2bfloat16(f));
}

// ---------- problem constants ----------
#define B_   2
#define T_   2048
#define H_   1536
#define NH_  8
#define HD_  256
#define ND_  2048   // NH*HD
#define NQKV 2560   // NH*HD + 2*HD

// ---------- f32 -> bf16 elementwise (n8 = n/8) ----------
__global__ __launch_bounds__(256) void cvt_f32_bf16(
        const float* __restrict__ src, __hip_bfloat16* __restrict__ dst, int n8) {
    int i = blockIdx.x * 256 + threadIdx.x;
    if (i >= n8) return;
    const float4* s4 = reinterpret_cast<const float4*>(src) + (size_t)i * 2;
    float4 a = s4[0], b = s4[1];
    short4 o0, o1;
    o0.x = (short)f2bf(a.x); o0.y = (short)f2bf(a.y);
    o0.z = (short)f2bf(a.z); o0.w = (short)f2bf(a.w);
    o1.x = (short)f2bf(b.x); o1.y = (short)f2bf(b.y);
    o1.z = (short)f2bf(b.z); o1.w = (short)f2bf(b.w);
    short4* d4 = reinterpret_cast<short4*>(dst) + (size_t)i * 2;
    d4[0] = o0; d4[1] = o1;
}

// ---------- fused QKV weight transpose: f32 (H x C) -> bf16 (C x H) ---------
__global__ __launch_bounds__(256) void transpose_qkv_f32_bf16(
        const float* __restrict__ Wq, const float* __restrict__ Wk,
        const float* __restrict__ Wv, __hip_bfloat16* __restrict__ dst) {
    __shared__ float tile[32][33];
    const int bx = blockIdx.x;           // 0..79 col-tiles of 32
    const float* src;
    int C, c0, orow0;
    if (bx < 64)      { src = Wq; C = ND_; c0 = bx * 32;        orow0 = c0; }
    else if (bx < 72) { src = Wk; C = HD_; c0 = (bx - 64) * 32; orow0 = ND_ + c0; }
    else              { src = Wv; C = HD_; c0 = (bx - 72) * 32; orow0 = ND_ + HD_ + c0; }
    const int r0 = blockIdx.y * 32;
    int tx = threadIdx.x & 31, ty = threadIdx.x >> 5;  // 32 x 8
#pragma unroll
    for (int i = 0; i < 32; i += 8)
        tile[ty + i][tx] = src[(size_t)(r0 + ty + i) * C + c0 + tx];
    __syncthreads();
#pragma unroll
    for (int i = 0; i < 32; i += 8)
        dst[(size_t)(orow0 + ty + i) * H_ + r0 + tx] =
            __float2bfloat16(tile[tx][ty + i]);
}

// ---------- transpose f32 (R x C) -> bf16 (C x R) ---------------------------
__global__ __launch_bounds__(256) void transpose_f32_bf16(
        const float* __restrict__ src, __hip_bfloat16* __restrict__ dst,
        int R, int C) {
    __shared__ float tile[32][33];
    int c0 = blockIdx.x * 32, r0 = blockIdx.y * 32;
    int tx = threadIdx.x & 31, ty = threadIdx.x >> 5;  // 32 x 8
#pragma unroll
    for (int i = 0; i < 32; i += 8)
        tile[ty + i][tx] = src[(size_t)(r0 + ty + i) * C + c0 + tx];
    __syncthreads();
#pragma unroll
    for (int i = 0; i < 32; i += 8)
        dst[(size_t)(c0 + ty + i) * R + r0 + tx] = __float2bfloat16(tile[tx][ty + i]);
}

// ---------- strided-src bf16 transpose: src(R x C, pitch ss) -> dst(C x R) --
__global__ __launch_bounds__(256) void transpose_bf16_s(
        const __hip_bfloat16* __restrict__ src, __hip_bfloat16* __restrict__ dst,
        int R, int C, int ss) {
    __shared__ __hip_bfloat16 tile[32][33];
    int c0 = blockIdx.x * 32, r0 = blockIdx.y * 32;
    int tx = threadIdx.x & 31, ty = threadIdx.x >> 5;
#pragma unroll
    for (int i = 0; i < 32; i += 8)
        tile[ty + i][tx] = src[(size_t)(r0 + ty + i) * ss + c0 + tx];
    __syncthreads();
#pragma unroll
    for (int i = 0; i < 32; i += 8)
        dst[(size_t)(c0 + ty + i) * R + r0 + tx] = tile[tx][ty + i];
}

// ---------- GEMM: C(MxN) = A(MxK) * Bt(NxK)^T, bf16 in, f32 acc -------------
// 128x128 tile, dbuf LDS, T4 counted-vmcnt + T1 XCD swizzle (round-14 form).
template <bool F32OUT>
__global__ __launch_bounds__(256) void gemm_bt(
        const __hip_bfloat16* __restrict__ A, const __hip_bfloat16* __restrict__ Bt,
        void* __restrict__ Cp, int M, int N, int K) {
    __shared__ char smem[32768];
    const int tid  = threadIdx.x;
    const int lane = tid & 63;
    const int w    = tid >> 6;
    const int wm   = w >> 1, wn = w & 1;

    // XCD swizzle: consecutive swizzled blocks land on the same XCD L2.
    const int gx  = gridDim.x;
    const int nwg = gx * gridDim.y;
    int lin = blockIdx.x + gx * blockIdx.y;
    int swz = (lin & 7) * (nwg >> 3) + (lin >> 3);
    const int m0 = (swz / gx) * 128, n0 = (swz % gx) * 128;

    f32x4 acc[4][4] = {};

    auto STAGE = [&](int bsel, int k0) {
        char* As = smem + bsel * 16384;
        char* Bs = As + 8192;
#pragma unroll
        for (int it = 0; it < 2; ++it) {
            int o   = it * 4096 + tid * 16;
            int row = o >> 6;
            int cb  = (o & 63) ^ (((o >> 7) & 3) << 4);
            gload_lds16(A  + (size_t)(m0 + row) * K + k0 + (cb >> 1),
                        As + it * 4096 + w * 1024);
            gload_lds16(Bt + (size_t)(n0 + row) * K + k0 + (cb >> 1),
                        Bs + it * 4096 + w * 1024);
        }
    };

    const int nk = K >> 5;
    STAGE(0, 0);
    for (int ik = 0; ik < nk; ++ik) {
        if (ik + 1 < nk) {
            STAGE((ik + 1) & 1, (ik + 1) << 5);
            asm volatile("s_waitcnt vmcnt(4)" ::: "memory");
        } else {
            asm volatile("s_waitcnt vmcnt(0)" ::: "memory");
        }
        __builtin_amdgcn_s_barrier();
        __builtin_amdgcn_sched_barrier(0);

        const char* As = smem + (ik & 1) * 16384;
        const char* Bs = As + 8192;

        bf16x8 af[4], bfr[4];
#pragma unroll
        for (int i = 0; i < 4; ++i) {
            int ar = wm * 64 + i * 16 + (lane & 15);
            int q  = ar * 64 + ((lane >> 4) << 4);
            af[i]  = *(const bf16x8*)(As + (q ^ (((q >> 7) & 3) << 4)));
            int br = wn * 64 + i * 16 + (lane & 15);
            int p  = br * 64 + ((lane >> 4) << 4);
            bfr[i] = *(const bf16x8*)(Bs + (p ^ (((p >> 7) & 3) << 4)));
        }
#pragma unroll
        for (int i = 0; i < 4; ++i)
#pragma unroll
            for (int j = 0; j < 4; ++j)
                acc[i][j] = mfma16(af[i], bfr[j], acc[i][j]);

        if (ik + 1 < nk) __builtin_amdgcn_s_barrier();  // buf-reuse fence
    }

#pragma unroll
    for (int i = 0; i < 4; ++i) {
        int rbase = m0 + wm * 64 + i * 16 + ((lane >> 4) << 2);
#pragma unroll
        for (int j = 0; j < 4; ++j) {
            int col = n0 + wn * 64 + j * 16 + (lane & 15);
#pragma unroll
            for (int r = 0; r < 4; ++r) {
                if (F32OUT)
                    ((float*)Cp)[(size_t)(rbase + r) * N + col] = acc[i][j][r];
                else
                    ((__hip_bfloat16*)Cp)[(size_t)(rbase + r) * N + col] =
                        __float2bfloat16(acc[i][j][r]);
            }
        }
    }
}

// ---------- RMSNorm + RoPE; reads fused QKV rows (pitch 2560) ---------------
__global__ __launch_bounds__(256) void norm_rope(
        const __hip_bfloat16* __restrict__ QKV,
        const float* __restrict__ cosT, const float* __restrict__ sinT,
        const int* __restrict__ positions,
        const float* __restrict__ qw, const float* __restrict__ kw,
        __hip_bfloat16* __restrict__ Qn, __hip_bfloat16* __restrict__ Kn) {
    int gw   = blockIdx.x * 4 + (threadIdx.x >> 6);
    int lane = threadIdx.x & 63;
    int bt   = gw / 9;
    int r    = gw - bt * 9;
    int b    = bt >> 11, t = bt & 2047;

    const __hip_bfloat16* src = QKV + (size_t)bt * NQKV + (r < 8 ? r * HD_ : ND_);
    const float* w;
    __hip_bfloat16* dst;
    float sc;
    if (r < 8) {
        w   = qw;
        dst = Qn + (((size_t)(b * NH_ + r) * T_) + t) * HD_;
        sc  = 0.0901684400555590f;  // log2(e)/16
    } else {
        w   = kw;
        dst = Kn + (size_t)bt * HD_;
        sc  = 1.0f;
    }

    short4 raw = *reinterpret_cast<const short4*>(src + lane * 4);
    float v[4];
    v[0] = bf2f((unsigned short)raw.x); v[1] = bf2f((unsigned short)raw.y);
    v[2] = bf2f((unsigned short)raw.z); v[3] = bf2f((unsigned short)raw.w);

    float ss = v[0]*v[0] + v[1]*v[1] + v[2]*v[2] + v[3]*v[3];
#pragma unroll
    for (int d = 1; d < 64; d <<= 1) ss += __shfl_xor(ss, d);
    float rms = rsqrtf(ss * (1.0f / HD_) + 1e-6f);

    int pos = positions[t];
    float4 c4 = *reinterpret_cast<const float4*>(cosT + (size_t)pos * 128 + (lane & 31) * 4);
    float4 s4 = *reinterpret_cast<const float4*>(sinT + (size_t)pos * 128 + (lane & 31) * 4);
    float cv[4] = { c4.x, c4.y, c4.z, c4.w };
    float sv[4] = { s4.x, s4.y, s4.z, s4.w };

    float4 w4 = *reinterpret_cast<const float4*>(w + lane * 4);
    float wv[4] = { w4.x, w4.y, w4.z, w4.w };

    float nf[4], out[4];
#pragma unroll
    for (int j = 0; j < 4; ++j) nf[j] = v[j] * rms * wv[j];
#pragma unroll
    for (int j = 0; j < 4; ++j) {
        float pf = __shfl_xor(nf[j], 32);
        out[j] = (lane < 32) ? (nf[j] * cv[j] - pf * sv[j])
                             : (nf[j] * cv[j] + pf * sv[j]);
    }
    short4 o4;
    o4.x = (short)f2bf(out[0] * sc); o4.y = (short)f2bf(out[1] * sc);
    o4.z = (short)f2bf(out[2] * sc); o4.w = (short)f2bf(out[3] * sc);
    *reinterpret_cast<short4*>(dst + lane * 4) = o4;
}

// ---------- split-KV flash attention: QBLK=128, 8 waves, T15 pipeline -------
// No-max valid: |S| <= 16 hard bound after RMSNorm. l via ones-fragment MFMA.
// T15 phase pipeline: QK(i+1) [MFMA] is placed ADJACENT to SM(i) [VALU/exp2]
// so the scheduler dual-issues across pipes; PV(i) follows. Barriers lockstep
// waves, so cross-wave overlap never happens — this intra-wave interleave is
// the only way to overlap the (measured-additive) phases.
#define NPAIR 40
__global__ __launch_bounds__(512) void flash_attn_split(
        const __hip_bfloat16* __restrict__ Qn, const __hip_bfloat16* __restrict__ Kn,
        const __hip_bfloat16* __restrict__ Vt,
        __hip_bfloat16* __restrict__ Opart, float* __restrict__ ml) {
    __shared__ char smem[2 * 16384 + 2 * 16384 + 8 * 1536];  // 77824 B
    // K buf b:  smem + b*16384          [32][256] bf16, 16B-slot ^= row&31
    // V buf b:  smem + 32768 + b*16384  [256][32] bf16, 16B-slot ^= (row>>1)&3
    char* Ps = smem + 65536;             // per wave [16][48] bf16

    const int tid = threadIdx.x, lane = tid & 63, wid = tid >> 6;  // wid 0..7
    const int p = blockIdx.x, bh = blockIdx.y;
    const int b = bh >> 3;

    int qt, c;
    if (p < 4)       { qt = p;                   c = 0; }
    else if (p < 12) { qt = 4 + ((p - 4) >> 1);  c = (p - 4) & 1; }
    else if (p < 24) { qt = 8 + (p - 12) / 3;    c = (p - 12) % 3; }
    else             { qt = 12 + ((p - 24) >> 2); c = (p - 24) & 3; }

    const int kv0 = c * 512;
    const int kv1 = min(kv0 + 512, (qt + 1) * 128);
    const int q0  = qt * 128 + wid * 16;
    const int nst = (kv1 - kv0) >> 5;   // >= 4 always

    const __hip_bfloat16* Qbase = Qn + ((size_t)bh * T_ + q0) * HD_;
    const __hip_bfloat16* Kb    = Kn + (size_t)b * T_ * HD_;
    const __hip_bfloat16* Vb    = Vt + (size_t)b * HD_ * T_;

    bf16x8 qf[8];
#pragma unroll
    for (int ks = 0; ks < 8; ++ks)
        qf[ks] = *(const bf16x8*)(Qbase + (size_t)(lane & 15) * HD_ + ks * 32 +
                                  ((lane >> 4) << 3));

    // ones B-fragment: B[k][0] = 1, else 0  -> row-sum lands in output col 0
    bf16x8 onesf;
    {
        __bf16 one = (__bf16)1.0f, zro = (__bf16)0.0f;
        __bf16 val = ((lane & 15) == 0) ? one : zro;
#pragma unroll
        for (int i = 0; i < 8; ++i) onesf[i] = val;
    }

    f32x4 acc[16] = {};
    f32x4 accl = {};

    auto STAGE = [&](int bsel, int kbb) {   // 4 vmem instructions / thread
        char* Kd = smem + bsel * 16384;
        char* Vd = smem + 32768 + bsel * 16384;
#pragma unroll
        for (int it = 0; it < 2; ++it) {
            int o = it * 8192 + tid * 16;
            {   // K tile [32][256]
                int row = o >> 9;
                int cb  = (o & 511) ^ ((row & 31) << 4);
                gload_lds16(Kb + (size_t)(kbb + row) * HD_ + (cb >> 1),
                            Kd + it * 8192 + wid * 1024);
            }
            {   // V^T tile [256][32]
                int row = o >> 6;
                int cb  = (o & 63) ^ (((o >> 7) & 3) << 4);
                gload_lds16(Vb + (size_t)row * T_ + kbb + (cb >> 1),
                            Vd + it * 8192 + wid * 1024);
            }
        }
    };

    auto QK = [&](int i, f32x4 (&s)[2]) {   // S = Q K^T for tile i
        const char* Ksb = smem + (i & 1) * 16384;
#pragma unroll
        for (int cf = 0; cf < 2; ++cf) {
#pragma unroll
            for (int ks = 0; ks < 8; ++ks) {
                int krow = cf * 16 + (lane & 15);
                int q    = krow * 512 + ks * 64 + ((lane >> 4) << 4);
                int sw   = q ^ (((q >> 9) & 31) << 4);
                bf16x8 kf = *(const bf16x8*)(Ksb + sw);
                s[cf] = mfma16(qf[ks], kf, s[cf]);
            }
        }
    };

    auto SM = [&](int i, f32x4 (&s)[2]) -> bf16x8 {  // masked exp2 -> P frag
        const int kb = kv0 + (i << 5);
        const bool nm = (kb + 31 > q0);
        __hip_bfloat16* pw = (__hip_bfloat16*)(Ps + wid * 1536);
#pragma unroll
        for (int r = 0; r < 4; ++r) {
            int rw = ((lane >> 4) << 2) + r;
            float s0 = s[0][r], s1 = s[1][r];
            if (nm) {
                int qrow = q0 + rw;
                if (kb + (lane & 15) > qrow)      s0 = -1e30f;
                if (kb + 16 + (lane & 15) > qrow) s1 = -1e30f;
            }
            pw[rw * 48 + (lane & 15)]      = __float2bfloat16(exp2f(s0));
            pw[rw * 48 + 16 + (lane & 15)] = __float2bfloat16(exp2f(s1));
        }
        // per-wave ds_write -> ds_read; compiler inserts lgkmcnt wait
        return *(const bf16x8*)(Ps + wid * 1536 + (lane & 15) * 96 +
                                ((lane >> 4) << 4));
    };

    auto PV = [&](int i, bf16x8 pf) {
        const char* Vsb = smem + 32768 + (i & 1) * 16384;
        accl = mfma16(pf, onesf, accl);   // row sums
#pragma unroll
        for (int nf = 0; nf < 16; ++nf) {
            int vrow = nf * 16 + (lane & 15);
            int q    = vrow * 64 + ((lane >> 4) << 4);
            int sw   = q ^ (((q >> 7) & 3) << 4);
            bf16x8 vf = *(const bf16x8*)(Vsb + sw);
            acc[nf] = mfma16(pf, vf, acc[nf]);
        }
    };

    // ---- T15 pipeline: sP holds S(i); QK(i+1) runs adjacent to SM(i) ----
    f32x4 sP[2] = {};
    STAGE(0, kv0);
    asm volatile("s_waitcnt vmcnt(0)" ::: "memory");
    __builtin_amdgcn_s_barrier();           // tile 0 resident everywhere
    STAGE(1, kv0 + 32);                     // buf1 untouched: no race
    __builtin_amdgcn_s_setprio(1);
    QK(0, sP);
    __builtin_amdgcn_s_setprio(0);

    for (int i = 0; i + 1 < nst; ++i) {
        asm volatile("s_waitcnt vmcnt(0)" ::: "memory");  // tile i+1 landed (mine)
        __builtin_amdgcn_s_barrier();                     // ... and everyone's
        __builtin_amdgcn_sched_barrier(0);

        // QK(i+1) [MFMA] + SM(i) [VALU/exp2]: independent, adjacent -> the
        // scheduler interleaves them across pipes.
        f32x4 sN[2] = {};
        __builtin_amdgcn_s_setprio(1);
        QK(i + 1, sN);
        bf16x8 pf = SM(i, sP);
        PV(i, pf);
        __builtin_amdgcn_s_setprio(0);

        __builtin_amdgcn_s_barrier();       // all waves done reading tile i
        if (i + 2 < nst) STAGE(i & 1, kv0 + ((i + 2) << 5));  // overwrite tile i
        sP[0] = sN[0]; sP[1] = sN[1];
    }
    // epilogue: last tile's SM + PV
    {
        bf16x8 pf = SM(nst - 1, sP);
        __builtin_amdgcn_s_setprio(1);
        PV(nst - 1, pf);
        __builtin_amdgcn_s_setprio(0);
    }

    // write unnormalized partial + row sums
    const int slot = bh * NPAIR + p;
    __hip_bfloat16* ob = Opart + (size_t)slot * (128 * 256);
#pragma unroll
    for (int r = 0; r < 4; ++r) {
        int rw = wid * 16 + ((lane >> 4) << 2) + r;   // 0..127
        __hip_bfloat16* orow = ob + (size_t)rw * 256;
#pragma unroll
        for (int nf = 0; nf < 16; ++nf)
            orow[nf * 16 + (lane & 15)] = __float2bfloat16(acc[nf][r]);
        if ((lane & 15) == 0) ml[slot * 128 + rw] = accl[r];
    }
}

// ---------- combine partials -> Obuf (plain sum, then normalize) ------------
// Grid: 256 blocks = (bh 16) x (qt 16); 256 threads: row = t>>1, half = t&1.
__global__ __launch_bounds__(256) void attn_combine(
        const __hip_bfloat16* __restrict__ Opart, const float* __restrict__ ml,
        __hip_bfloat16* __restrict__ Obuf) {
    const int bid = blockIdx.x;
    const int bh = bid >> 4, qt = bid & 15;
    const int b = bh >> 3, h = bh & 7;

    int ps, np;
    if (qt < 4)       { ps = qt;                 np = 1; }
    else if (qt < 8)  { ps = 4 + 2 * (qt - 4);   np = 2; }
    else if (qt < 12) { ps = 12 + 3 * (qt - 8);  np = 3; }
    else              { ps = 24 + 4 * (qt - 12); np = 4; }
    const int slot0 = bh * NPAIR + ps;

    const int t = threadIdx.x;
    const int row = t >> 1, half = t & 1;

    float L = 0.0f;
    for (int i = 0; i < np; ++i) L += ml[(slot0 + i) * 128 + row];
    float rL = 1.0f / L;

    __hip_bfloat16* orow = Obuf + ((size_t)(b * T_ + qt * 128 + row)) * ND_ +
                           h * HD_ + half * 128;
#pragma unroll
    for (int cc = 0; cc < 16; ++cc) {
        float a[8] = {0,0,0,0,0,0,0,0};
        for (int i = 0; i < np; ++i) {
            const __hip_bfloat16* pr = Opart + (size_t)(slot0 + i) * (128 * 256) +
                                       (size_t)row * 256 + half * 128 + cc * 8;
            short4 v0 = *reinterpret_cast<const short4*>(pr);
            short4 v1 = *reinterpret_cast<const short4*>(pr + 4);
            a[0] += bf2f((unsigned short)v0.x);
            a[1] += bf2f((unsigned short)v0.y);
            a[2] += bf2f((unsigned short)v0.z);
            a[3] += bf2f((unsigned short)v0.w);
            a[4] += bf2f((unsigned short)v1.x);
            a[5] += bf2f((unsigned short)v1.y);
            a[6] += bf2f((unsigned short)v1.z);
            a[7] += bf2f((unsigned short)v1.w);
        }
        short4 o0, o1;
        o0.x = (short)f2bf(a[0] * rL); o0.y = (short)f2bf(a[1] * rL);
        o0.z = (short)f2bf(a[2] * rL); o0.w = (short)f2bf(a[3] * rL);
        o1.x = (short)f2bf(a[4] * rL); o1.y = (short)f2bf(a[5] * rL);
        o1.z = (short)f2bf(a[6] * rL); o1.w = (short)f2bf(a[7] * rL);
        *reinterpret_cast<short4*>(orow + cc * 8)     = o0;
        *reinterpret_cast<short4*>(orow + cc * 8 + 4) = o1;
    }
}

// ---------- launch ----------
extern "C" void kernel_launch(void* const* d_in, const int* in_sizes, int n_in,
                              void* d_out, int out_size, void* d_ws, size_t ws_size,
                              hipStream_t stream) {
    const float* x    = (const float*)d_in[0];
    const int*   pos  = (const int*)d_in[1];
    const float* cosT = (const float*)d_in[2];
    const float* sinT = (const float*)d_in[3];
    // d_in[4] = causal_mask (unused; causal applied analytically)
    const float* Wq = (const float*)d_in[5];
    const float* Wk = (const float*)d_in[6];
    const float* Wv = (const float*)d_in[7];
    const float* Wo = (const float*)d_in[8];
    const float* qw = (const float*)d_in[9];
    const float* kw = (const float*)d_in[10];

    // ---- workspace layout (overlay; total 69,861,376 B) ----
    char* ws0 = (char*)d_ws;
    __hip_bfloat16* WqkvT  = (__hip_bfloat16*)(ws0 + 0);          //  7,864,320
    __hip_bfloat16* xb     = (__hip_bfloat16*)(ws0 + 7864320);    // 12,582,912
    __hip_bfloat16* QKVraw = (__hip_bfloat16*)(ws0 + 20447232);   // 20,971,520
    __hip_bfloat16* Opart  = (__hip_bfloat16*)(ws0 + 0);          // 41,943,040
    float*          ml     = (float*)(ws0 + 41943040);            //    327,680
    __hip_bfloat16* WoT    = (__hip_bfloat16*)(ws0 + 42598400);   //  6,291,456
    __hip_bfloat16* Qn     = (__hip_bfloat16*)(ws0 + 48889856);   // 16,777,216
    __hip_bfloat16* Obuf   = Qn;  // Qn dead once flash_attn_split completes;
                                  // only attn_combine (stream-ordered after)
                                  // writes Obuf.
    __hip_bfloat16* Kn     = (__hip_bfloat16*)(ws0 + 65667072);   //  2,097,152
    __hip_bfloat16* Vt     = (__hip_bfloat16*)(ws0 + 67764224);   //  2,097,152
    float* out = (float*)d_out;

    const int MT = B_ * T_;  // 4096

    // 0) x -> bf16
    cvt_f32_bf16<<<(MT * H_ / 8 + 255) / 256, 256, 0, stream>>>(x, xb, MT * H_ / 8);

    // 1) weight transposes: fused Wq/Wk/Wv -> WqkvT (one launch) + Wo -> WoT
    transpose_qkv_f32_bf16<<<dim3(80, H_ / 32), 256, 0, stream>>>(
        Wq, Wk, Wv, WqkvT);
    transpose_f32_bf16<<<dim3(H_ / 32, ND_ / 32), 256, 0, stream>>>(
        Wo, WoT, ND_, H_);

    // 2) fused QKV projection: (4096 x 1536) @ (2560 x 1536)^T
    gemm_bt<false><<<dim3(NQKV / 128, MT / 128), 256, 0, stream>>>(
        xb, WqkvT, QKVraw, MT, NQKV, H_);

    // 3) RMSNorm + RoPE (q pre-scaled by log2e/16)
    norm_rope<<<(MT * 9) / 4, 256, 0, stream>>>(
        QKVraw, cosT, sinT, pos, qw, kw, Qn, Kn);

    // 4) V transpose per batch: rows (T,HD) at pitch 2560 -> (HD, T)
    for (int b = 0; b < B_; ++b)
        transpose_bf16_s<<<dim3(HD_ / 32, T_ / 32), 256, 0, stream>>>(
            QKVraw + (size_t)b * T_ * NQKV + ND_ + HD_,
            Vt + (size_t)b * HD_ * T_, T_, HD_, NQKV);

    // 5) split-KV attention + combine (combine is the sole Obuf writer)
    flash_attn_split<<<dim3(NPAIR, B_ * NH_), 512, 0, stream>>>(
        Qn, Kn, Vt, Opart, ml);
    attn_combine<<<B_ * NH_ * 16, 256, 0, stream>>>(Opart, ml, Obuf);

    // 6) output projection -> f32 out
    gemm_bt<true><<<dim3(H_ / 128, MT / 128), 256, 0, stream>>>(
        Obuf, WoT, out, MT, H_, ND_);
}

// Round 16
// 235.323 us; speedup vs baseline: 1.0603x; 1.0603x over previous
//
#include <hip/hip_runtime.h>
#include <hip/hip_bf16.h>

// ---------- types ----------
typedef __bf16 bf16x8 __attribute__((ext_vector_type(8)));
typedef float  f32x4  __attribute__((ext_vector_type(4)));

__device__ __forceinline__ f32x4 mfma16(bf16x8 a, bf16x8 b, f32x4 c) {
    return __builtin_amdgcn_mfma_f32_16x16x32_bf16(a, b, c, 0, 0, 0);
}

__device__ __forceinline__ void gload_lds16(const void* g, void* l) {
    __builtin_amdgcn_global_load_lds(
        (const __attribute__((address_space(1))) void*)g,
        (__attribute__((address_space(3))) void*)l, 16, 0, 0);
}

__device__ __forceinline__ float bf2f(unsigned short u) {
    unsigned int x = (unsigned int)u << 16;
    return __builtin_bit_cast(float, x);
}
__device__ __forceinline__ unsigned short f2bf(float f) {
    return __builtin_bit_cast(unsigned short, __float2bfloat16(f));
}

// ---------- problem constants ----------
#define B_   2
#define T_   2048
#define H_   1536
#define NH_  8
#define HD_  256
#define ND_  2048   // NH*HD
#define NQKV 2560   // NH*HD + 2*HD

// ---------- f32 -> bf16 elementwise (n8 = n/8) ----------
__global__ __launch_bounds__(256) void cvt_f32_bf16(
        const float* __restrict__ src, __hip_bfloat16* __restrict__ dst, int n8) {
    int i = blockIdx.x * 256 + threadIdx.x;
    if (i >= n8) return;
    const float4* s4 = reinterpret_cast<const float4*>(src) + (size_t)i * 2;
    float4 a = s4[0], b = s4[1];
    short4 o0, o1;
    o0.x = (short)f2bf(a.x); o0.y = (short)f2bf(a.y);
    o0.z = (short)f2bf(a.z); o0.w = (short)f2bf(a.w);
    o1.x = (short)f2bf(b.x); o1.y = (short)f2bf(b.y);
    o1.z = (short)f2bf(b.z); o1.w = (short)f2bf(b.w);
    short4* d4 = reinterpret_cast<short4*>(dst) + (size_t)i * 2;
    d4[0] = o0; d4[1] = o1;
}

// ---------- fused QKV weight transpose: f32 (H x C) -> bf16 (C x H) ---------
// One launch for Wq (C=2048), Wk (C=256), Wv (C=256): blockIdx.x selects
// source; outputs are packed contiguously in WqkvT (2560 rows of H).
__global__ __launch_bounds__(256) void transpose_qkv_f32_bf16(
        const float* __restrict__ Wq, const float* __restrict__ Wk,
        const float* __restrict__ Wv, __hip_bfloat16* __restrict__ dst) {
    __shared__ float tile[32][33];
    const int bx = blockIdx.x;           // 0..79 col-tiles of 32
    const float* src;
    int C, c0, orow0;
    if (bx < 64)      { src = Wq; C = ND_; c0 = bx * 32;        orow0 = c0; }
    else if (bx < 72) { src = Wk; C = HD_; c0 = (bx - 64) * 32; orow0 = ND_ + c0; }
    else              { src = Wv; C = HD_; c0 = (bx - 72) * 32; orow0 = ND_ + HD_ + c0; }
    const int r0 = blockIdx.y * 32;
    int tx = threadIdx.x & 31, ty = threadIdx.x >> 5;  // 32 x 8
#pragma unroll
    for (int i = 0; i < 32; i += 8)
        tile[ty + i][tx] = src[(size_t)(r0 + ty + i) * C + c0 + tx];
    __syncthreads();
#pragma unroll
    for (int i = 0; i < 32; i += 8)
        dst[(size_t)(orow0 + ty + i) * H_ + r0 + tx] =
            __float2bfloat16(tile[tx][ty + i]);
}

// ---------- transpose f32 (R x C) -> bf16 (C x R) ---------------------------
__global__ __launch_bounds__(256) void transpose_f32_bf16(
        const float* __restrict__ src, __hip_bfloat16* __restrict__ dst,
        int R, int C) {
    __shared__ float tile[32][33];
    int c0 = blockIdx.x * 32, r0 = blockIdx.y * 32;
    int tx = threadIdx.x & 31, ty = threadIdx.x >> 5;  // 32 x 8
#pragma unroll
    for (int i = 0; i < 32; i += 8)
        tile[ty + i][tx] = src[(size_t)(r0 + ty + i) * C + c0 + tx];
    __syncthreads();
#pragma unroll
    for (int i = 0; i < 32; i += 8)
        dst[(size_t)(c0 + ty + i) * R + r0 + tx] = __float2bfloat16(tile[tx][ty + i]);
}

// ---------- strided-src bf16 transpose: src(R x C, pitch ss) -> dst(C x R) --
__global__ __launch_bounds__(256) void transpose_bf16_s(
        const __hip_bfloat16* __restrict__ src, __hip_bfloat16* __restrict__ dst,
        int R, int C, int ss) {
    __shared__ __hip_bfloat16 tile[32][33];
    int c0 = blockIdx.x * 32, r0 = blockIdx.y * 32;
    int tx = threadIdx.x & 31, ty = threadIdx.x >> 5;
#pragma unroll
    for (int i = 0; i < 32; i += 8)
        tile[ty + i][tx] = src[(size_t)(r0 + ty + i) * ss + c0 + tx];
    __syncthreads();
#pragma unroll
    for (int i = 0; i < 32; i += 8)
        dst[(size_t)(c0 + ty + i) * R + r0 + tx] = tile[tx][ty + i];
}

// ---------- GEMM: C(MxN) = A(MxK) * Bt(NxK)^T, bf16 in, f32 acc -------------
// 128x128 tile, double-buffered LDS, T4 counted-vmcnt pipeline (round-9 WIN)
// + T1 XCD-aware block swizzle (requires nwg % 8 == 0; both call sites OK).
template <bool F32OUT>
__global__ __launch_bounds__(256) void gemm_bt(
        const __hip_bfloat16* __restrict__ A, const __hip_bfloat16* __restrict__ Bt,
        void* __restrict__ Cp, int M, int N, int K) {
    __shared__ char smem[32768];
    const int tid  = threadIdx.x;
    const int lane = tid & 63;
    const int w    = tid >> 6;
    const int wm   = w >> 1, wn = w & 1;

    // XCD swizzle: consecutive swizzled blocks land on the same XCD L2.
    const int gx  = gridDim.x;
    const int nwg = gx * gridDim.y;
    int lin = blockIdx.x + gx * blockIdx.y;
    int swz = (lin & 7) * (nwg >> 3) + (lin >> 3);
    const int m0 = (swz / gx) * 128, n0 = (swz % gx) * 128;

    f32x4 acc[4][4] = {};

    auto STAGE = [&](int bsel, int k0) {
        char* As = smem + bsel * 16384;
        char* Bs = As + 8192;
#pragma unroll
        for (int it = 0; it < 2; ++it) {
            int o   = it * 4096 + tid * 16;
            int row = o >> 6;
            int cb  = (o & 63) ^ (((o >> 7) & 3) << 4);
            gload_lds16(A  + (size_t)(m0 + row) * K + k0 + (cb >> 1),
                        As + it * 4096 + w * 1024);
            gload_lds16(Bt + (size_t)(n0 + row) * K + k0 + (cb >> 1),
                        Bs + it * 4096 + w * 1024);
        }
    };

    const int nk = K >> 5;
    STAGE(0, 0);
    for (int ik = 0; ik < nk; ++ik) {
        if (ik + 1 < nk) {
            STAGE((ik + 1) & 1, (ik + 1) << 5);
            asm volatile("s_waitcnt vmcnt(4)" ::: "memory");
        } else {
            asm volatile("s_waitcnt vmcnt(0)" ::: "memory");
        }
        __builtin_amdgcn_s_barrier();
        __builtin_amdgcn_sched_barrier(0);

        const char* As = smem + (ik & 1) * 16384;
        const char* Bs = As + 8192;

        bf16x8 af[4], bfr[4];
#pragma unroll
        for (int i = 0; i < 4; ++i) {
            int ar = wm * 64 + i * 16 + (lane & 15);
            int q  = ar * 64 + ((lane >> 4) << 4);
            af[i]  = *(const bf16x8*)(As + (q ^ (((q >> 7) & 3) << 4)));
            int br = wn * 64 + i * 16 + (lane & 15);
            int p  = br * 64 + ((lane >> 4) << 4);
            bfr[i] = *(const bf16x8*)(Bs + (p ^ (((p >> 7) & 3) << 4)));
        }
#pragma unroll
        for (int i = 0; i < 4; ++i)
#pragma unroll
            for (int j = 0; j < 4; ++j)
                acc[i][j] = mfma16(af[i], bfr[j], acc[i][j]);

        if (ik + 1 < nk) __builtin_amdgcn_s_barrier();  // buf-reuse fence
    }

#pragma unroll
    for (int i = 0; i < 4; ++i) {
        int rbase = m0 + wm * 64 + i * 16 + ((lane >> 4) << 2);
#pragma unroll
        for (int j = 0; j < 4; ++j) {
            int col = n0 + wn * 64 + j * 16 + (lane & 15);
#pragma unroll
            for (int r = 0; r < 4; ++r) {
                if (F32OUT)
                    ((float*)Cp)[(size_t)(rbase + r) * N + col] = acc[i][j][r];
                else
                    ((__hip_bfloat16*)Cp)[(size_t)(rbase + r) * N + col] =
                        __float2bfloat16(acc[i][j][r]);
            }
        }
    }
}

// ---------- RMSNorm + RoPE; reads fused QKV rows (pitch 2560) ---------------
__global__ __launch_bounds__(256) void norm_rope(
        const __hip_bfloat16* __restrict__ QKV,
        const float* __restrict__ cosT, const float* __restrict__ sinT,
        const int* __restrict__ positions,
        const float* __restrict__ qw, const float* __restrict__ kw,
        __hip_bfloat16* __restrict__ Qn, __hip_bfloat16* __restrict__ Kn) {
    int gw   = blockIdx.x * 4 + (threadIdx.x >> 6);
    int lane = threadIdx.x & 63;
    int bt   = gw / 9;
    int r    = gw - bt * 9;
    int b    = bt >> 11, t = bt & 2047;

    const __hip_bfloat16* src = QKV + (size_t)bt * NQKV + (r < 8 ? r * HD_ : ND_);
    const float* w;
    __hip_bfloat16* dst;
    float sc;
    if (r < 8) {
        w   = qw;
        dst = Qn + (((size_t)(b * NH_ + r) * T_) + t) * HD_;
        sc  = 0.0901684400555590f;  // log2(e)/16
    } else {
        w   = kw;
        dst = Kn + (size_t)bt * HD_;
        sc  = 1.0f;
    }

    short4 raw = *reinterpret_cast<const short4*>(src + lane * 4);
    float v[4];
    v[0] = bf2f((unsigned short)raw.x); v[1] = bf2f((unsigned short)raw.y);
    v[2] = bf2f((unsigned short)raw.z); v[3] = bf2f((unsigned short)raw.w);

    float ss = v[0]*v[0] + v[1]*v[1] + v[2]*v[2] + v[3]*v[3];
#pragma unroll
    for (int d = 1; d < 64; d <<= 1) ss += __shfl_xor(ss, d);
    float rms = rsqrtf(ss * (1.0f / HD_) + 1e-6f);

    int pos = positions[t];
    float4 c4 = *reinterpret_cast<const float4*>(cosT + (size_t)pos * 128 + (lane & 31) * 4);
    float4 s4 = *reinterpret_cast<const float4*>(sinT + (size_t)pos * 128 + (lane & 31) * 4);
    float cv[4] = { c4.x, c4.y, c4.z, c4.w };
    float sv[4] = { s4.x, s4.y, s4.z, s4.w };

    float4 w4 = *reinterpret_cast<const float4*>(w + lane * 4);
    float wv[4] = { w4.x, w4.y, w4.z, w4.w };

    float nf[4], out[4];
#pragma unroll
    for (int j = 0; j < 4; ++j) nf[j] = v[j] * rms * wv[j];
#pragma unroll
    for (int j = 0; j < 4; ++j) {
        float pf = __shfl_xor(nf[j], 32);
        out[j] = (lane < 32) ? (nf[j] * cv[j] - pf * sv[j])
                             : (nf[j] * cv[j] + pf * sv[j]);
    }
    short4 o4;
    o4.x = (short)f2bf(out[0] * sc); o4.y = (short)f2bf(out[1] * sc);
    o4.z = (short)f2bf(out[2] * sc); o4.w = (short)f2bf(out[3] * sc);
    *reinterpret_cast<short4*>(dst + lane * 4) = o4;
}

// ---------- split-KV flash attention: QBLK=128, 8 waves (round-10 proven) ---
// No-max valid: |S| <= 16 hard bound after RMSNorm. l via ones-fragment MFMA.
// T4: dbuf + counted vmcnt(4) + raw barriers (prefetch stays in flight).
#define NPAIR 40
__global__ __launch_bounds__(512) void flash_attn_split(
        const __hip_bfloat16* __restrict__ Qn, const __hip_bfloat16* __restrict__ Kn,
        const __hip_bfloat16* __restrict__ Vt,
        __hip_bfloat16* __restrict__ Opart, float* __restrict__ ml) {
    __shared__ char smem[2 * 16384 + 2 * 16384 + 8 * 1536];  // 77824 B
    // K buf b:  smem + b*16384          [32][256] bf16, 16B-slot ^= row&31
    // V buf b:  smem + 32768 + b*16384  [256][32] bf16, 16B-slot ^= (row>>1)&3
    char* Ps = smem + 65536;             // per wave [16][48] bf16

    const int tid = threadIdx.x, lane = tid & 63, wid = tid >> 6;  // wid 0..7
    const int p = blockIdx.x, bh = blockIdx.y;
    const int b = bh >> 3;

    int qt, c;
    if (p < 4)       { qt = p;                   c = 0; }
    else if (p < 12) { qt = 4 + ((p - 4) >> 1);  c = (p - 4) & 1; }
    else if (p < 24) { qt = 8 + (p - 12) / 3;    c = (p - 12) % 3; }
    else             { qt = 12 + ((p - 24) >> 2); c = (p - 24) & 3; }

    const int kv0 = c * 512;
    const int kv1 = min(kv0 + 512, (qt + 1) * 128);
    const int q0  = qt * 128 + wid * 16;
    const int nst = (kv1 - kv0) >> 5;

    const __hip_bfloat16* Qbase = Qn + ((size_t)bh * T_ + q0) * HD_;
    const __hip_bfloat16* Kb    = Kn + (size_t)b * T_ * HD_;
    const __hip_bfloat16* Vb    = Vt + (size_t)b * HD_ * T_;

    bf16x8 qf[8];
#pragma unroll
    for (int ks = 0; ks < 8; ++ks)
        qf[ks] = *(const bf16x8*)(Qbase + (size_t)(lane & 15) * HD_ + ks * 32 +
                                  ((lane >> 4) << 3));

    // ones B-fragment: B[k][0] = 1, else 0  -> row-sum lands in output col 0
    bf16x8 onesf;
    {
        __bf16 one = (__bf16)1.0f, zro = (__bf16)0.0f;
        __bf16 val = ((lane & 15) == 0) ? one : zro;
#pragma unroll
        for (int i = 0; i < 8; ++i) onesf[i] = val;
    }

    f32x4 acc[16] = {};
    f32x4 accl = {};

    auto STAGE = [&](int bsel, int kbb) {   // 4 vmem instructions / thread
        char* Kd = smem + bsel * 16384;
        char* Vd = smem + 32768 + bsel * 16384;
#pragma unroll
        for (int it = 0; it < 2; ++it) {
            int o = it * 8192 + tid * 16;
            {   // K tile [32][256]
                int row = o >> 9;
                int cb  = (o & 511) ^ ((row & 31) << 4);
                gload_lds16(Kb + (size_t)(kbb + row) * HD_ + (cb >> 1),
                            Kd + it * 8192 + wid * 1024);
            }
            {   // V^T tile [256][32]
                int row = o >> 6;
                int cb  = (o & 63) ^ (((o >> 7) & 3) << 4);
                gload_lds16(Vb + (size_t)row * T_ + kbb + (cb >> 1),
                            Vd + it * 8192 + wid * 1024);
            }
        }
    };

    STAGE(0, kv0);
    for (int i = 0; i < nst; ++i) {
        const int kb = kv0 + (i << 5);
        if (i + 1 < nst) {
            STAGE((i + 1) & 1, kb + 32);               // prefetch next tile
            asm volatile("s_waitcnt vmcnt(4)" ::: "memory");  // tile-i landed
        } else {
            asm volatile("s_waitcnt vmcnt(0)" ::: "memory");
        }
        __builtin_amdgcn_s_barrier();                  // all waves ready
        __builtin_amdgcn_sched_barrier(0);

        const char* Ksb = smem + (i & 1) * 16384;
        const char* Vsb = smem + 32768 + (i & 1) * 16384;

        // S = Q K^T  (16 x 32), pre-scaled so P = exp2(S)
        f32x4 s[2] = {};
        __builtin_amdgcn_s_setprio(1);
#pragma unroll
        for (int cf = 0; cf < 2; ++cf) {
#pragma unroll
            for (int ks = 0; ks < 8; ++ks) {
                int krow = cf * 16 + (lane & 15);
                int q    = krow * 512 + ks * 64 + ((lane >> 4) << 4);
                int sw   = q ^ (((q >> 9) & 31) << 4);
                bf16x8 kf = *(const bf16x8*)(Ksb + sw);
                s[cf] = mfma16(qf[ks], kf, s[cf]);
            }
        }
        __builtin_amdgcn_s_setprio(0);

        // mask only on diagonal steps (wave-uniform test); P = exp2(S)
        const bool nm = (kb + 31 > q0);
        __hip_bfloat16* pw = (__hip_bfloat16*)(Ps + wid * 1536);
#pragma unroll
        for (int r = 0; r < 4; ++r) {
            int rw = ((lane >> 4) << 2) + r;
            float s0 = s[0][r], s1 = s[1][r];
            if (nm) {
                int qrow = q0 + rw;
                if (kb + (lane & 15) > qrow)      s0 = -1e30f;
                if (kb + 16 + (lane & 15) > qrow) s1 = -1e30f;
            }
            pw[rw * 48 + (lane & 15)]      = __float2bfloat16(exp2f(s0));
            pw[rw * 48 + 16 + (lane & 15)] = __float2bfloat16(exp2f(s1));
        }
        // P is per-wave: same-wave ds_write -> ds_read, compiler lgkmcnt.

        bf16x8 pf = *(const bf16x8*)(Ps + wid * 1536 + (lane & 15) * 96 +
                                     ((lane >> 4) << 4));
        __builtin_amdgcn_s_setprio(1);
        accl = mfma16(pf, onesf, accl);   // row sums
#pragma unroll
        for (int nf = 0; nf < 16; ++nf) {
            int vrow = nf * 16 + (lane & 15);
            int q    = vrow * 64 + ((lane >> 4) << 4);
            int sw   = q ^ (((q >> 7) & 3) << 4);
            bf16x8 vf = *(const bf16x8*)(Vsb + sw);
            acc[nf] = mfma16(pf, vf, acc[nf]);
        }
        __builtin_amdgcn_s_setprio(0);

        if (i + 1 < nst) __builtin_amdgcn_s_barrier();  // buf-reuse fence
    }

    // write unnormalized partial + row sums
    const int slot = bh * NPAIR + p;
    __hip_bfloat16* ob = Opart + (size_t)slot * (128 * 256);
#pragma unroll
    for (int r = 0; r < 4; ++r) {
        int rw = wid * 16 + ((lane >> 4) << 2) + r;   // 0..127
        __hip_bfloat16* orow = ob + (size_t)rw * 256;
#pragma unroll
        for (int nf = 0; nf < 16; ++nf)
            orow[nf * 16 + (lane & 15)] = __float2bfloat16(acc[nf][r]);
        if ((lane & 15) == 0) ml[slot * 128 + rw] = accl[r];
    }
}

// ---------- combine partials -> Obuf (plain sum, then normalize) ------------
// Grid: 256 blocks = (bh 16) x (qt 16); 256 threads: row = t>>1, half = t&1.
__global__ __launch_bounds__(256) void attn_combine(
        const __hip_bfloat16* __restrict__ Opart, const float* __restrict__ ml,
        __hip_bfloat16* __restrict__ Obuf) {
    const int bid = blockIdx.x;
    const int bh = bid >> 4, qt = bid & 15;
    const int b = bh >> 3, h = bh & 7;

    int ps, np;
    if (qt < 4)       { ps = qt;                 np = 1; }
    else if (qt < 8)  { ps = 4 + 2 * (qt - 4);   np = 2; }
    else if (qt < 12) { ps = 12 + 3 * (qt - 8);  np = 3; }
    else              { ps = 24 + 4 * (qt - 12); np = 4; }
    const int slot0 = bh * NPAIR + ps;

    const int t = threadIdx.x;
    const int row = t >> 1, half = t & 1;

    float L = 0.0f;
    for (int i = 0; i < np; ++i) L += ml[(slot0 + i) * 128 + row];
    float rL = 1.0f / L;

    __hip_bfloat16* orow = Obuf + ((size_t)(b * T_ + qt * 128 + row)) * ND_ +
                           h * HD_ + half * 128;
#pragma unroll
    for (int cc = 0; cc < 16; ++cc) {
        float a[8] = {0,0,0,0,0,0,0,0};
        for (int i = 0; i < np; ++i) {
            const __hip_bfloat16* pr = Opart + (size_t)(slot0 + i) * (128 * 256) +
                                       (size_t)row * 256 + half * 128 + cc * 8;
            short4 v0 = *reinterpret_cast<const short4*>(pr);
            short4 v1 = *reinterpret_cast<const short4*>(pr + 4);
            a[0] += bf2f((unsigned short)v0.x);
            a[1] += bf2f((unsigned short)v0.y);
            a[2] += bf2f((unsigned short)v0.z);
            a[3] += bf2f((unsigned short)v0.w);
            a[4] += bf2f((unsigned short)v1.x);
            a[5] += bf2f((unsigned short)v1.y);
            a[6] += bf2f((unsigned short)v1.z);
            a[7] += bf2f((unsigned short)v1.w);
        }
        short4 o0, o1;
        o0.x = (short)f2bf(a[0] * rL); o0.y = (short)f2bf(a[1] * rL);
        o0.z = (short)f2bf(a[2] * rL); o0.w = (short)f2bf(a[3] * rL);
        o1.x = (short)f2bf(a[4] * rL); o1.y = (short)f2bf(a[5] * rL);
        o1.z = (short)f2bf(a[6] * rL); o1.w = (short)f2bf(a[7] * rL);
        *reinterpret_cast<short4*>(orow + cc * 8)     = o0;
        *reinterpret_cast<short4*>(orow + cc * 8 + 4) = o1;
    }
}

// ---------- launch ----------
extern "C" void kernel_launch(void* const* d_in, const int* in_sizes, int n_in,
                              void* d_out, int out_size, void* d_ws, size_t ws_size,
                              hipStream_t stream) {
    const float* x    = (const float*)d_in[0];
    const int*   pos  = (const int*)d_in[1];
    const float* cosT = (const float*)d_in[2];
    const float* sinT = (const float*)d_in[3];
    // d_in[4] = causal_mask (unused; causal applied analytically)
    const float* Wq = (const float*)d_in[5];
    const float* Wk = (const float*)d_in[6];
    const float* Wv = (const float*)d_in[7];
    const float* Wo = (const float*)d_in[8];
    const float* qw = (const float*)d_in[9];
    const float* kw = (const float*)d_in[10];

    // ---- workspace layout (overlay; total 69,861,376 B) ----
    char* ws0 = (char*)d_ws;
    __hip_bfloat16* WqkvT  = (__hip_bfloat16*)(ws0 + 0);          //  7,864,320
    __hip_bfloat16* xb     = (__hip_bfloat16*)(ws0 + 7864320);    // 12,582,912
    __hip_bfloat16* QKVraw = (__hip_bfloat16*)(ws0 + 20447232);   // 20,971,520
    __hip_bfloat16* Opart  = (__hip_bfloat16*)(ws0 + 0);          // 41,943,040
    float*          ml     = (float*)(ws0 + 41943040);            //    327,680
    __hip_bfloat16* WoT    = (__hip_bfloat16*)(ws0 + 42598400);   //  6,291,456
    __hip_bfloat16* Qn     = (__hip_bfloat16*)(ws0 + 48889856);   // 16,777,216
    __hip_bfloat16* Obuf   = Qn;  // Qn dead once flash_attn_split completes;
                                  // only attn_combine (stream-ordered after)
                                  // writes Obuf.
    __hip_bfloat16* Kn     = (__hip_bfloat16*)(ws0 + 65667072);   //  2,097,152
    __hip_bfloat16* Vt     = (__hip_bfloat16*)(ws0 + 67764224);   //  2,097,152
    float* out = (float*)d_out;

    const int MT = B_ * T_;  // 4096

    // 0) x -> bf16
    cvt_f32_bf16<<<(MT * H_ / 8 + 255) / 256, 256, 0, stream>>>(x, xb, MT * H_ / 8);

    // 1) weight transposes: fused Wq/Wk/Wv -> WqkvT (one launch) + Wo -> WoT
    transpose_qkv_f32_bf16<<<dim3(80, H_ / 32), 256, 0, stream>>>(
        Wq, Wk, Wv, WqkvT);
    transpose_f32_bf16<<<dim3(H_ / 32, ND_ / 32), 256, 0, stream>>>(
        Wo, WoT, ND_, H_);

    // 2) fused QKV projection: (4096 x 1536) @ (2560 x 1536)^T
    gemm_bt<false><<<dim3(NQKV / 128, MT / 128), 256, 0, stream>>>(
        xb, WqkvT, QKVraw, MT, NQKV, H_);

    // 3) RMSNorm + RoPE (q pre-scaled by log2e/16)
    norm_rope<<<(MT * 9) / 4, 256, 0, stream>>>(
        QKVraw, cosT, sinT, pos, qw, kw, Qn, Kn);

    // 4) V transpose per batch: rows (T,HD) at pitch 2560 -> (HD, T)
    for (int b = 0; b < B_; ++b)
        transpose_bf16_s<<<dim3(HD_ / 32, T_ / 32), 256, 0, stream>>>(
            QKVraw + (size_t)b * T_ * NQKV + ND_ + HD_,
            Vt + (size_t)b * HD_ * T_, T_, HD_, NQKV);

    // 5) split-KV attention + combine (combine is the sole Obuf writer)
    flash_attn_split<<<dim3(NPAIR, B_ * NH_), 512, 0, stream>>>(
        Qn, Kn, Vt, Opart, ml);
    attn_combine<<<B_ * NH_ * 16, 256, 0, stream>>>(Opart, ml, Obuf);

    // 6) output projection -> f32 out
    gemm_bt<true><<<dim3(H_ / 128, MT / 128), 256, 0, stream>>>(
        Obuf, WoT, out, MT, H_, ND_);
}